// Round 1
// baseline (877.649 us; speedup 1.0000x reference)
//
#include <hip/hip_runtime.h>
#include <hip/hip_bf16.h>
#include <math.h>

// Problem constants (B=1)
#define D_CH   256
#define NHEAD  4
#define DHEAD  64
#define NPTS   4096
#define BN_RSQ 0.99999500003749963f   // 1/sqrt(1 + 1e-5)

// ---------------------------------------------------------------------------
// Generic f32 tiled GEMM with fused epilogue.
//   C[M][N] = epi( A[M][K] * B[K][N] )
//   epi: v = acc + bias[m]; if gamma: v = v*(gamma[m]*BN_RSQ) + beta[m];
//        if relu: v = max(v,0); if resid: v += resid[m][n]
// Tile: 64(M) x 128(N) x 64(K), 256 threads, per-thread 8x4 accumulator.
// Requires M%64==0, N%128==0, K%64==0 (holds for all uses here).
// ---------------------------------------------------------------------------
__global__ __launch_bounds__(256) void gemm_epi(
    const float* __restrict__ A, const float* __restrict__ B,
    float* __restrict__ C, int M, int N, int K,
    const float* __restrict__ bias, const float* __restrict__ gamma,
    const float* __restrict__ beta, int relu, const float* __restrict__ resid)
{
    __shared__ __align__(16) float As[64][65];   // [k][m], +1 pad
    __shared__ __align__(16) float Bs[64][128];  // [k][n]

    const int tid = threadIdx.x;
    const int n0 = blockIdx.x * 128;
    const int m0 = blockIdx.y * 64;
    const int c = tid & 31;   // col group: cols c*4 .. c*4+3
    const int r = tid >> 5;   // row group: rows r*8 .. r*8+7

    float acc[8][4];
#pragma unroll
    for (int i = 0; i < 8; ++i)
#pragma unroll
        for (int j = 0; j < 4; ++j) acc[i][j] = 0.0f;

    for (int k0 = 0; k0 < K; k0 += 64) {
        // Stage A tile transposed: As[k][m] = A[m0+m][k0+k]
#pragma unroll
        for (int p = 0; p < 16; ++p) {
            int idx = p * 256 + tid;
            int m = idx >> 6, kk = idx & 63;
            As[kk][m] = A[(size_t)(m0 + m) * K + k0 + kk];
        }
        // Stage B tile: Bs[k][n]
#pragma unroll
        for (int p = 0; p < 8; ++p) {
            int idx = p * 256 + tid;
            int kk = idx >> 5, n4 = idx & 31;
            *(float4*)&Bs[kk][n4 * 4] =
                *(const float4*)&B[(size_t)(k0 + kk) * N + n0 + n4 * 4];
        }
        __syncthreads();

#pragma unroll 8
        for (int kk = 0; kk < 64; ++kk) {
            float4 bv = *(float4*)&Bs[kk][c * 4];
            float bb[4] = {bv.x, bv.y, bv.z, bv.w};
#pragma unroll
            for (int i = 0; i < 8; ++i) {
                float a = As[kk][r * 8 + i];
#pragma unroll
                for (int j = 0; j < 4; ++j) acc[i][j] = fmaf(a, bb[j], acc[i][j]);
            }
        }
        __syncthreads();
    }

    // Epilogue
#pragma unroll
    for (int i = 0; i < 8; ++i) {
        int m = m0 + r * 8 + i;
        float bi = bias[m];
        float sc = 1.0f, sh = 0.0f;
        if (gamma) { sc = gamma[m] * BN_RSQ; sh = beta[m]; }
#pragma unroll
        for (int j = 0; j < 4; ++j) {
            int n = n0 + c * 4 + j;
            float v = acc[i][j] + bi;
            if (gamma) v = v * sc + sh;
            if (relu)  v = fmaxf(v, 0.0f);
            if (resid) v += resid[(size_t)m * N + n];
            C[(size_t)m * N + n] = v;
        }
    }
}

// ---------------------------------------------------------------------------
// Flash attention with multiplicative spatial mask (f32).
// Per block: one head, 64-query tile. 256 threads. Key tiles of 128.
//   s[q][k] = (Q[:,q].K[:,k]) * 0.125 * S[q][k]; softmax over k; acc = P*V^T
// Q/K/V layout: [H][DH][N] (rows h*64+d of the [256][4096] ws buffers).
// ---------------------------------------------------------------------------
__global__ __launch_bounds__(256, 1) void attn_flash(
    const float* __restrict__ Q, const float* __restrict__ K,
    const float* __restrict__ V, const float* __restrict__ S,
    float* __restrict__ msg)
{
    const int h  = blockIdx.y;
    const int q0 = blockIdx.x * 64;
    const int tid = threadIdx.x;

    const float* Qh = Q + (size_t)h * DHEAD * NPTS;
    const float* Kh = K + (size_t)h * DHEAD * NPTS;
    const float* Vh = V + (size_t)h * DHEAD * NPTS;

    __shared__ __align__(16) float Qs[DHEAD][68];      // [d][q]
    __shared__ __align__(16) float Ks[DHEAD][128];     // [d][k]
    __shared__ __align__(16) float VsT[128][68];       // [k][d]
    __shared__ __align__(16) float SsPs[128 * 68];     // union: Ss[q][k] (64x128) then Ps[k][q] (128x68)
    __shared__ __align__(16) float red[16][68];        // [kgroup][q] reduction buffer
    __shared__ float mx[64], ls[64], cf[64];

    const int cq = tid & 15;   // q group: q = cq*4 + jq
    const int rk = tid >> 4;   // QK: k group (k = rk*8+jk); PV: d group (d = rk*4+jd)

    // Load Q tile once
#pragma unroll
    for (int p = 0; p < 16; ++p) {
        int idx = p * 256 + tid;
        int d = idx >> 6, q = idx & 63;
        Qs[d][q] = Qh[(size_t)d * NPTS + q0 + q];
    }
    if (tid < 64) { mx[tid] = -3.0e38f; ls[tid] = 0.0f; }

    float acc[4][4];
#pragma unroll
    for (int i = 0; i < 4; ++i)
#pragma unroll
        for (int j = 0; j < 4; ++j) acc[i][j] = 0.0f;

    __syncthreads();

    for (int k0 = 0; k0 < NPTS; k0 += 128) {
        // --- A: stage K, V^T, S tiles -------------------------------------
#pragma unroll
        for (int p = 0; p < 8; ++p) {            // Ks[d][k]
            int idx = p * 256 + tid;
            int d = idx >> 5, k4 = idx & 31;
            *(float4*)&Ks[d][k4 * 4] =
                *(const float4*)&Kh[(size_t)d * NPTS + k0 + k4 * 4];
        }
#pragma unroll
        for (int p = 0; p < 32; ++p) {           // VsT[k][d] (transpose)
            int idx = p * 256 + tid;
            int d = idx >> 7, kk = idx & 127;
            VsT[kk][d] = Vh[(size_t)d * NPTS + k0 + kk];
        }
#pragma unroll
        for (int p = 0; p < 8; ++p) {            // Ss[q][k]
            int idx = p * 256 + tid;
            int q = idx >> 5, k4 = idx & 31;
            *(float4*)&SsPs[q * 128 + k4 * 4] =
                *(const float4*)&S[(size_t)(q0 + q) * NPTS + k0 + k4 * 4];
        }
        __syncthreads();  // B1

        // --- B: scores s[4q][8k] ------------------------------------------
        float s[4][8];
#pragma unroll
        for (int i = 0; i < 4; ++i)
#pragma unroll
            for (int j = 0; j < 8; ++j) s[i][j] = 0.0f;

#pragma unroll 4
        for (int d = 0; d < DHEAD; ++d) {
            float4 qv = *(float4*)&Qs[d][cq * 4];
            float qa[4] = {qv.x, qv.y, qv.z, qv.w};
            float4 ka = *(float4*)&Ks[d][rk * 8];
            float4 kb = *(float4*)&Ks[d][rk * 8 + 4];
            float kk[8] = {ka.x, ka.y, ka.z, ka.w, kb.x, kb.y, kb.z, kb.w};
#pragma unroll
            for (int i = 0; i < 4; ++i)
#pragma unroll
                for (int j = 0; j < 8; ++j) s[i][j] = fmaf(qa[i], kk[j], s[i][j]);
        }
        // scale + spatial mask; local per-q max
        float lm[4];
#pragma unroll
        for (int i = 0; i < 4; ++i) {
            lm[i] = -3.0e38f;
#pragma unroll
            for (int j = 0; j < 8; ++j) {
                float sm = SsPs[(cq * 4 + i) * 128 + rk * 8 + j];
                s[i][j] = s[i][j] * 0.125f * sm;
                lm[i] = fmaxf(lm[i], s[i][j]);
            }
            red[rk][cq * 4 + i] = lm[i];
        }
        __syncthreads();  // B2

        // --- D: per-q running max + rescale factor ------------------------
        if (tid < 64) {
            int q = tid;
            float tm = red[0][q];
#pragma unroll
            for (int t = 1; t < 16; ++t) tm = fmaxf(tm, red[t][q]);
            float mo = mx[q];
            float mn = fmaxf(mo, tm);
            cf[q] = __expf(mo - mn);
            mx[q] = mn;
        }
        __syncthreads();  // B3

        // --- E: p = exp(s - m), write Ps[k][q], partial sums --------------
#pragma unroll
        for (int i = 0; i < 4; ++i) {
            int q = cq * 4 + i;
            float mq = mx[q];
            float ps = 0.0f;
            float pv[8];
#pragma unroll
            for (int j = 0; j < 8; ++j) {
                pv[j] = __expf(s[i][j] - mq);
                ps += pv[j];
            }
#pragma unroll
            for (int j = 0; j < 8; ++j)
                SsPs[(rk * 8 + j) * 68 + q] = pv[j];
            red[rk][q] = ps;
        }
        __syncthreads();  // B4

        // --- F: l update --------------------------------------------------
        if (tid < 64) {
            int q = tid;
            float t = 0.0f;
#pragma unroll
            for (int u = 0; u < 16; ++u) t += red[u][q];
            ls[q] = ls[q] * cf[q] + t;
        }

        // --- G: PV accumulate, acc[4q][4d] --------------------------------
        float c_[4];
#pragma unroll
        for (int i = 0; i < 4; ++i) c_[i] = cf[cq * 4 + i];
#pragma unroll
        for (int i = 0; i < 4; ++i)
#pragma unroll
            for (int j = 0; j < 4; ++j) acc[i][j] *= c_[i];

#pragma unroll 4
        for (int k = 0; k < 128; ++k) {
            float4 pw = *(float4*)&SsPs[k * 68 + cq * 4];
            float pa[4] = {pw.x, pw.y, pw.z, pw.w};
            float4 vv = *(float4*)&VsT[k][rk * 4];
            float va[4] = {vv.x, vv.y, vv.z, vv.w};
#pragma unroll
            for (int i = 0; i < 4; ++i)
#pragma unroll
                for (int j = 0; j < 4; ++j) acc[i][j] = fmaf(pa[i], va[j], acc[i][j]);
        }
        __syncthreads();  // B5: protect tiles for next iteration
    }

    // Final normalize + store: msg[h*64 + d][q0 + q]
#pragma unroll
    for (int i = 0; i < 4; ++i) {
        int q = cq * 4 + i;
        float inv = 1.0f / ls[q];
#pragma unroll
        for (int j = 0; j < 4; ++j) {
            int d = rk * 4 + j;
            msg[((size_t)(h * DHEAD + d)) * NPTS + q0 + q] = acc[i][j] * inv;
        }
    }
}

// ---------------------------------------------------------------------------
extern "C" void kernel_launch(void* const* d_in, const int* in_sizes, int n_in,
                              void* d_out, int out_size, void* d_ws, size_t ws_size,
                              hipStream_t stream) {
    const float* x  = (const float*)d_in[0];   // [256][4096]
    const float* S  = (const float*)d_in[1];   // [4096][4096]
    const float* Wq = (const float*)d_in[2];
    const float* bq = (const float*)d_in[3];
    const float* Wk = (const float*)d_in[4];
    const float* bk = (const float*)d_in[5];
    const float* Wv = (const float*)d_in[6];
    const float* bv = (const float*)d_in[7];
    const float* W1 = (const float*)d_in[8];
    const float* b1 = (const float*)d_in[9];
    const float* g1 = (const float*)d_in[10];
    const float* be1= (const float*)d_in[11];
    const float* W2 = (const float*)d_in[12];
    const float* b2 = (const float*)d_in[13];
    const float* g2 = (const float*)d_in[14];
    const float* be2= (const float*)d_in[15];
    const float* W3 = (const float*)d_in[16];
    const float* b3 = (const float*)d_in[17];

    float* ws = (float*)d_ws;
    float* Qb  = ws;                    // 256*4096
    float* Kb  = ws + 1048576;
    float* Vb  = ws + 2097152;
    float* msg = ws + 3145728;
    float* h1  = ws + 4194304;          // 128*4096
    float* h2  = ws + 4718592;

    // QKV projections
    gemm_epi<<<dim3(32, 4), 256, 0, stream>>>(Wq, x, Qb, 256, NPTS, 256, bq, nullptr, nullptr, 0, nullptr);
    gemm_epi<<<dim3(32, 4), 256, 0, stream>>>(Wk, x, Kb, 256, NPTS, 256, bk, nullptr, nullptr, 0, nullptr);
    gemm_epi<<<dim3(32, 4), 256, 0, stream>>>(Wv, x, Vb, 256, NPTS, 256, bv, nullptr, nullptr, 0, nullptr);

    // Fused masked attention (flash-style)
    attn_flash<<<dim3(64, 4), 256, 0, stream>>>(Qb, Kb, Vb, S, msg);

    // Message MLP: conv->BN->ReLU, conv->BN->ReLU, conv (+residual into d_out)
    gemm_epi<<<dim3(32, 2), 256, 0, stream>>>(W1, msg, h1, 128, NPTS, 256, b1, g1, be1, 1, nullptr);
    gemm_epi<<<dim3(32, 2), 256, 0, stream>>>(W2, h1, h2, 128, NPTS, 128, b2, g2, be2, 1, nullptr);
    gemm_epi<<<dim3(32, 4), 256, 0, stream>>>(W3, h2, (float*)d_out, 256, NPTS, 128, b3, nullptr, nullptr, 0, x);
}

// Round 2
// 408.708 us; speedup vs baseline: 2.1474x; 2.1474x over previous
//
#include <hip/hip_runtime.h>
#include <hip/hip_bf16.h>
#include <math.h>

#define D_CH   256
#define NHEAD  4
#define DHEAD  64
#define NPTS   4096
#define BN_RSQ 0.99999500003749963f   // 1/sqrt(1 + 1e-5)

typedef __attribute__((ext_vector_type(4))) float f32x4;
typedef __attribute__((ext_vector_type(8))) short bf16x8;
typedef unsigned short ushort_t;

__device__ __forceinline__ ushort_t f2bf(float x) {
    unsigned int b = __float_as_uint(x);
    return (ushort_t)((b + 0x7FFF + ((b >> 16) & 1)) >> 16);  // RNE
}

// ---------------------------------------------------------------------------
// f32 tiled GEMM with fused epilogue (unchanged core from round 1).
// out_mode: 0 = f32 row-major C[m][n]
//           1 = bf16 transposed Qt/Kt layout: O[(m>>6)][n][m&63]  ([H][N][DH])
//           2 = bf16 row-major O[m][n]                            ([H][DH][N])
// ---------------------------------------------------------------------------
__global__ __launch_bounds__(256) void gemm_epi(
    const float* __restrict__ A, const float* __restrict__ B,
    void* __restrict__ Cout, int M, int N, int K,
    const float* __restrict__ bias, const float* __restrict__ gamma,
    const float* __restrict__ beta, int relu, const float* __restrict__ resid,
    int out_mode)
{
    __shared__ __align__(16) float As[64][65];   // [k][m], +1 pad
    __shared__ __align__(16) float Bs[64][128];  // [k][n]

    const int tid = threadIdx.x;
    const int n0 = blockIdx.x * 128;
    const int m0 = blockIdx.y * 64;
    const int c = tid & 31;
    const int r = tid >> 5;

    float acc[8][4];
#pragma unroll
    for (int i = 0; i < 8; ++i)
#pragma unroll
        for (int j = 0; j < 4; ++j) acc[i][j] = 0.0f;

    for (int k0 = 0; k0 < K; k0 += 64) {
#pragma unroll
        for (int p = 0; p < 16; ++p) {
            int idx = p * 256 + tid;
            int m = idx >> 6, kk = idx & 63;
            As[kk][m] = A[(size_t)(m0 + m) * K + k0 + kk];
        }
#pragma unroll
        for (int p = 0; p < 8; ++p) {
            int idx = p * 256 + tid;
            int kk = idx >> 5, n4 = idx & 31;
            *(float4*)&Bs[kk][n4 * 4] =
                *(const float4*)&B[(size_t)(k0 + kk) * N + n0 + n4 * 4];
        }
        __syncthreads();

#pragma unroll 8
        for (int kk = 0; kk < 64; ++kk) {
            float4 bv = *(float4*)&Bs[kk][c * 4];
            float bb[4] = {bv.x, bv.y, bv.z, bv.w};
#pragma unroll
            for (int i = 0; i < 8; ++i) {
                float a = As[kk][r * 8 + i];
#pragma unroll
                for (int j = 0; j < 4; ++j) acc[i][j] = fmaf(a, bb[j], acc[i][j]);
            }
        }
        __syncthreads();
    }

    float* Cf = (float*)Cout;
    ushort_t* Cu = (ushort_t*)Cout;
#pragma unroll
    for (int i = 0; i < 8; ++i) {
        int m = m0 + r * 8 + i;
        float bi = bias[m];
        float sc = 1.0f, sh = 0.0f;
        if (gamma) { sc = gamma[m] * BN_RSQ; sh = beta[m]; }
#pragma unroll
        for (int j = 0; j < 4; ++j) {
            int n = n0 + c * 4 + j;
            float v = acc[i][j] + bi;
            if (gamma) v = v * sc + sh;
            if (relu)  v = fmaxf(v, 0.0f);
            if (resid) v += resid[(size_t)m * N + n];
            if (out_mode == 0)      Cf[(size_t)m * N + n] = v;
            else if (out_mode == 1) Cu[((size_t)(m >> 6) * N + n) * 64 + (m & 63)] = f2bf(v);
            else                    Cu[(size_t)m * N + n] = f2bf(v);
        }
    }
}

// ---------------------------------------------------------------------------
// MFMA flash attention with multiplicative spatial mask.
// Block = (q-tile of 64) x head; 4 warps, each warp owns 16 queries.
// No barriers in the main loop: K/V/mask fragments read direct from
// global (L1/L2-resident per head); only a tiny per-warp LDS buffer for
// the P transpose (scores C-layout -> PV A-layout).
//
// Layouts (bf16): Qt,Kt = [H][N][DH]; Vt = [H][DH][N].
// MFMA 16x16x32 bf16 fragment maps (m89/m91 + §5 recipe):
//   A: row = lane&15, k = (lane>>4)*8 + e   (8 contiguous bf16 / lane)
//   B: col = lane&15, k = (lane>>4)*8 + e
//   C/D: col = lane&15, row = (lane>>4)*4 + reg
// ---------------------------------------------------------------------------
__global__ __launch_bounds__(256, 1) void attn_mfma(
    const ushort_t* __restrict__ Qt, const ushort_t* __restrict__ Kt,
    const ushort_t* __restrict__ Vt, const float* __restrict__ S,
    float* __restrict__ msg)
{
    __shared__ __align__(16) ushort_t P_lds[4][16][72];  // per-warp, padded rows

    const int tid  = threadIdx.x;
    const int w    = tid >> 6;
    const int lane = tid & 63;
    const int l15  = lane & 15;
    const int lhi  = lane >> 4;           // 0..3
    const int h    = blockIdx.y;
    const int q0   = blockIdx.x * 64 + w * 16;  // this warp's 16 queries

    const ushort_t* Kh = Kt + (size_t)h * NPTS * DHEAD;
    const ushort_t* Vh = Vt + (size_t)h * DHEAD * NPTS;

    // Q fragments: A-operand, rows = 16 queries, two K=32 halves of d
    bf16x8 qf0, qf1;
    {
        const ushort_t* qp = Qt + ((size_t)h * NPTS + q0 + l15) * DHEAD + lhi * 8;
        qf0 = *(const bf16x8*)qp;
        qf1 = *(const bf16x8*)(qp + 32);
    }

    f32x4 macc[4];                 // [dblk]: C rows q=lhi*4+r, col d=dblk*16+l15
#pragma unroll
    for (int db = 0; db < 4; ++db) macc[db] = (f32x4){0.f, 0.f, 0.f, 0.f};
    float mrun[4], lrun[4];
#pragma unroll
    for (int r = 0; r < 4; ++r) { mrun[r] = -3.0e38f; lrun[r] = 0.0f; }

    for (int k0 = 0; k0 < NPTS; k0 += 64) {
        // --- QK^T over 4 key-blocks of 16 ---------------------------------
        f32x4 sacc[4];
#pragma unroll
        for (int kb = 0; kb < 4; ++kb) {
            const ushort_t* kp = Kh + (size_t)(k0 + kb * 16 + l15) * DHEAD + lhi * 8;
            bf16x8 kf0 = *(const bf16x8*)kp;
            bf16x8 kf1 = *(const bf16x8*)(kp + 32);
            f32x4 z = (f32x4){0.f, 0.f, 0.f, 0.f};
            z = __builtin_amdgcn_mfma_f32_16x16x32_bf16(qf0, kf0, z, 0, 0, 0);
            z = __builtin_amdgcn_mfma_f32_16x16x32_bf16(qf1, kf1, z, 0, 0, 0);
            sacc[kb] = z;
        }

        // --- mask * scale, per-row online softmax stats --------------------
        float p[4][4];             // [kb][r]
        float tmax[4];
#pragma unroll
        for (int r = 0; r < 4; ++r) tmax[r] = -3.0e38f;
#pragma unroll
        for (int kb = 0; kb < 4; ++kb) {
#pragma unroll
            for (int r = 0; r < 4; ++r) {
                float mval = S[(size_t)(q0 + lhi * 4 + r) * NPTS + k0 + kb * 16 + l15];
                float sv = sacc[kb][r] * 0.125f * mval;
                p[kb][r] = sv;
                tmax[r] = fmaxf(tmax[r], sv);
            }
        }
        // reduce max over the 16 key-lanes (butterfly, stays in 16-lane group)
#pragma unroll
        for (int r = 0; r < 4; ++r) {
            tmax[r] = fmaxf(tmax[r], __shfl_xor(tmax[r], 1));
            tmax[r] = fmaxf(tmax[r], __shfl_xor(tmax[r], 2));
            tmax[r] = fmaxf(tmax[r], __shfl_xor(tmax[r], 4));
            tmax[r] = fmaxf(tmax[r], __shfl_xor(tmax[r], 8));
        }
        float cf[4], tsum[4];
#pragma unroll
        for (int r = 0; r < 4; ++r) {
            float mn = fmaxf(mrun[r], tmax[r]);
            cf[r] = __expf(mrun[r] - mn);
            mrun[r] = mn;
            float s_ = 0.0f;
#pragma unroll
            for (int kb = 0; kb < 4; ++kb) {
                p[kb][r] = __expf(p[kb][r] - mn);
                s_ += p[kb][r];
            }
            tsum[r] = s_;
        }
#pragma unroll
        for (int r = 0; r < 4; ++r) {
            tsum[r] += __shfl_xor(tsum[r], 1);
            tsum[r] += __shfl_xor(tsum[r], 2);
            tsum[r] += __shfl_xor(tsum[r], 4);
            tsum[r] += __shfl_xor(tsum[r], 8);
            lrun[r] = lrun[r] * cf[r] + tsum[r];
        }
        // rescale running PV accumulator
#pragma unroll
        for (int db = 0; db < 4; ++db)
#pragma unroll
            for (int r = 0; r < 4; ++r) macc[db][r] *= cf[r];

        // --- P (C-layout) -> bf16 -> per-warp LDS [q][k] --------------------
#pragma unroll
        for (int kb = 0; kb < 4; ++kb)
#pragma unroll
            for (int r = 0; r < 4; ++r)
                P_lds[w][lhi * 4 + r][kb * 16 + l15] = f2bf(p[kb][r]);
        // same-wave RAW through LDS: compiler inserts lgkmcnt wait

        // --- PV: 2 key-halves x 4 d-blocks ---------------------------------
#pragma unroll
        for (int m = 0; m < 2; ++m) {
            bf16x8 pf = *(const bf16x8*)&P_lds[w][l15][m * 32 + lhi * 8];
#pragma unroll
            for (int db = 0; db < 4; ++db) {
                const ushort_t* vp = Vh + (size_t)(db * 16 + l15) * NPTS
                                   + k0 + m * 32 + lhi * 8;
                bf16x8 vf = *(const bf16x8*)vp;
                macc[db] = __builtin_amdgcn_mfma_f32_16x16x32_bf16(pf, vf, macc[db], 0, 0, 0);
            }
        }
    }

    // --- normalize + store msg[h*64 + d][q] (f32, channel-major) -----------
    float inv[4];
#pragma unroll
    for (int r = 0; r < 4; ++r) inv[r] = 1.0f / lrun[r];
#pragma unroll
    for (int db = 0; db < 4; ++db) {
#pragma unroll
        for (int r = 0; r < 4; ++r) {
            msg[(size_t)(h * DHEAD + db * 16 + l15) * NPTS + q0 + lhi * 4 + r]
                = macc[db][r] * inv[r];
        }
    }
}

// ---------------------------------------------------------------------------
extern "C" void kernel_launch(void* const* d_in, const int* in_sizes, int n_in,
                              void* d_out, int out_size, void* d_ws, size_t ws_size,
                              hipStream_t stream) {
    const float* x  = (const float*)d_in[0];   // [256][4096]
    const float* S  = (const float*)d_in[1];   // [4096][4096]
    const float* Wq = (const float*)d_in[2];
    const float* bq = (const float*)d_in[3];
    const float* Wk = (const float*)d_in[4];
    const float* bk = (const float*)d_in[5];
    const float* Wv = (const float*)d_in[6];
    const float* bv = (const float*)d_in[7];
    const float* W1 = (const float*)d_in[8];
    const float* b1 = (const float*)d_in[9];
    const float* g1 = (const float*)d_in[10];
    const float* be1= (const float*)d_in[11];
    const float* W2 = (const float*)d_in[12];
    const float* b2 = (const float*)d_in[13];
    const float* g2 = (const float*)d_in[14];
    const float* be2= (const float*)d_in[15];
    const float* W3 = (const float*)d_in[16];
    const float* b3 = (const float*)d_in[17];

    char* ws = (char*)d_ws;
    ushort_t* Qt = (ushort_t*)(ws);                      // 2 MB  [H][N][64] bf16
    ushort_t* Kt = (ushort_t*)(ws + 2  * 1024 * 1024);   // 2 MB  [H][N][64]
    ushort_t* Vt = (ushort_t*)(ws + 4  * 1024 * 1024);   // 2 MB  [H][64][N]
    float*   msg = (float*)   (ws + 8  * 1024 * 1024);   // 4 MB  [256][4096]
    float*   h1  = (float*)   (ws + 12 * 1024 * 1024);   // 2 MB  [128][4096]
    float*   h2  = (float*)   (ws + 14 * 1024 * 1024);   // 2 MB  [128][4096]

    // QKV projections (f32 compute, bf16 fragment-layout outputs)
    gemm_epi<<<dim3(32, 4), 256, 0, stream>>>(Wq, x, Qt, 256, NPTS, 256, bq, nullptr, nullptr, 0, nullptr, 1);
    gemm_epi<<<dim3(32, 4), 256, 0, stream>>>(Wk, x, Kt, 256, NPTS, 256, bk, nullptr, nullptr, 0, nullptr, 1);
    gemm_epi<<<dim3(32, 4), 256, 0, stream>>>(Wv, x, Vt, 256, NPTS, 256, bv, nullptr, nullptr, 0, nullptr, 2);

    // MFMA flash attention
    attn_mfma<<<dim3(64, 4), 256, 0, stream>>>(Qt, Kt, Vt, S, msg);

    // Message MLP (f32)
    gemm_epi<<<dim3(32, 2), 256, 0, stream>>>(W1, msg, h1, 128, NPTS, 256, b1, g1, be1, 1, nullptr, 0);
    gemm_epi<<<dim3(32, 2), 256, 0, stream>>>(W2, h1, h2, 128, NPTS, 128, b2, g2, be2, 1, nullptr, 0);
    gemm_epi<<<dim3(32, 4), 256, 0, stream>>>(W3, h2, d_out, 256, NPTS, 128, b3, nullptr, nullptr, 0, x, 0);
}

// Round 3
// 199.150 us; speedup vs baseline: 4.4070x; 2.0523x over previous
//
#include <hip/hip_runtime.h>
#include <hip/hip_bf16.h>
#include <math.h>

#define D_CH   256
#define NHEAD  4
#define DHEAD  64
#define NPTS   4096
#define KSPLIT 4
#define KCHUNK (NPTS / KSPLIT)
#define BN_RSQ 0.99999500003749963f   // 1/sqrt(1 + 1e-5)

typedef __attribute__((ext_vector_type(4))) float f32x4;
typedef __attribute__((ext_vector_type(8))) short bf16x8;
typedef unsigned short ushort_t;

__device__ __forceinline__ ushort_t f2bf(float x) {
    unsigned int b = __float_as_uint(x);
    return (ushort_t)((b + 0x7FFF + ((b >> 16) & 1)) >> 16);  // RNE
}
__device__ __forceinline__ float bf2f(ushort_t u) {
    return __uint_as_float(((unsigned int)u) << 16);
}

// ---------------------------------------------------------------------------
// prep: transpose-cast x [256][4096] f32 -> xT [4096][256] bf16
// ---------------------------------------------------------------------------
__global__ __launch_bounds__(256) void transpose_cast(
    const float* __restrict__ x, ushort_t* __restrict__ xT)
{
    __shared__ float xs[64][65];
    const int tid = threadIdx.x;
    const int n0 = blockIdx.x * 64, k0 = blockIdx.y * 64;
#pragma unroll
    for (int p = 0; p < 16; ++p) {
        int kk = p * 4 + (tid >> 6), nn = tid & 63;
        xs[kk][nn] = x[(size_t)(k0 + kk) * NPTS + n0 + nn];
    }
    __syncthreads();
#pragma unroll
    for (int p = 0; p < 16; ++p) {
        int nn = p * 4 + (tid >> 6), kk = tid & 63;
        xT[(size_t)(n0 + nn) * D_CH + k0 + kk] = f2bf(xs[kk][nn]);
    }
}

// ---------------------------------------------------------------------------
// MFMA GEMM: C[m][n] = epi( sum_k A[m][k] * Bt[n][k] )
// A: f32 [M][K] (weights, cast to bf16 on the fly). Bt: bf16 [N][K].
// Block = 4 warps (2m x 2n), warp tile 32x32, block tile 64x64. No LDS.
// out_mode: 0 = f32 C[m][n] (+resid)
//           1 = bf16 Qt/Kt layout  Cu[((m>>6)*N + n)*64 + (m&63)]
//           2 = bf16 row-major     Cu[m*N + n]
//           3 = bf16 transposed    Cu[n*M + m]
// ---------------------------------------------------------------------------
__global__ __launch_bounds__(256) void gemm_mfma(
    const float* __restrict__ A, const ushort_t* __restrict__ Bt,
    void* __restrict__ Cout, int M, int N, int K,
    const float* __restrict__ bias, const float* __restrict__ gamma,
    const float* __restrict__ beta, int relu, const float* __restrict__ resid,
    int out_mode)
{
    const int tid = threadIdx.x;
    const int w = tid >> 6, lane = tid & 63, l15 = lane & 15, lhi = lane >> 4;
    const int wm = w >> 1, wn = w & 1;
    const int m0 = blockIdx.y * 64 + wm * 32;
    const int n0 = blockIdx.x * 64 + wn * 32;

    f32x4 acc[2][2];
#pragma unroll
    for (int i = 0; i < 2; ++i)
#pragma unroll
        for (int j = 0; j < 2; ++j) acc[i][j] = (f32x4){0.f, 0.f, 0.f, 0.f};

    for (int k0 = 0; k0 < K; k0 += 32) {
        bf16x8 af[2], bf[2];
#pragma unroll
        for (int mf = 0; mf < 2; ++mf) {
            const float* ap = A + (size_t)(m0 + mf * 16 + l15) * K + k0 + lhi * 8;
            float4 a0 = *(const float4*)ap;
            float4 a1 = *(const float4*)(ap + 4);
            bf16x8 t;
            t[0] = (short)f2bf(a0.x); t[1] = (short)f2bf(a0.y);
            t[2] = (short)f2bf(a0.z); t[3] = (short)f2bf(a0.w);
            t[4] = (short)f2bf(a1.x); t[5] = (short)f2bf(a1.y);
            t[6] = (short)f2bf(a1.z); t[7] = (short)f2bf(a1.w);
            af[mf] = t;
        }
#pragma unroll
        for (int nf = 0; nf < 2; ++nf)
            bf[nf] = *(const bf16x8*)&Bt[(size_t)(n0 + nf * 16 + l15) * K + k0 + lhi * 8];
#pragma unroll
        for (int mf = 0; mf < 2; ++mf)
#pragma unroll
            for (int nf = 0; nf < 2; ++nf)
                acc[mf][nf] = __builtin_amdgcn_mfma_f32_16x16x32_bf16(af[mf], bf[nf], acc[mf][nf], 0, 0, 0);
    }

    float* Cf = (float*)Cout;
    ushort_t* Cu = (ushort_t*)Cout;
#pragma unroll
    for (int mf = 0; mf < 2; ++mf) {
#pragma unroll
        for (int r = 0; r < 4; ++r) {
            int m = m0 + mf * 16 + lhi * 4 + r;
            float bi = bias[m];
            float sc = 1.0f, sh = 0.0f;
            if (gamma) { sc = gamma[m] * BN_RSQ; sh = beta[m]; }
#pragma unroll
            for (int nf = 0; nf < 2; ++nf) {
                int n = n0 + nf * 16 + l15;
                float v = acc[mf][nf][r] + bi;
                if (gamma) v = v * sc + sh;
                if (relu)  v = fmaxf(v, 0.0f);
                if (resid) v += resid[(size_t)m * N + n];
                if (out_mode == 0)      Cf[(size_t)m * N + n] = v;
                else if (out_mode == 1) Cu[((size_t)(m >> 6) * N + n) * 64 + (m & 63)] = f2bf(v);
                else if (out_mode == 2) Cu[(size_t)m * N + n] = f2bf(v);
                else                    Cu[(size_t)n * M + m] = f2bf(v);
            }
        }
    }
}

// ---------------------------------------------------------------------------
// MFMA flash attention, key-split. Block = (qtile 64, head, ksplit).
// 4 warps x 16 queries; each block scans KCHUNK keys; writes unnormalized
// partial acc (bf16) + running m,l (f32).
// Layouts: Qt,Kt = [H][N][DH] bf16; Vt = [H][DH][N] bf16.
// ---------------------------------------------------------------------------
__global__ __launch_bounds__(256, 1) void attn_mfma(
    const ushort_t* __restrict__ Qt, const ushort_t* __restrict__ Kt,
    const ushort_t* __restrict__ Vt, const float* __restrict__ S,
    ushort_t* __restrict__ pacc, float* __restrict__ pm, float* __restrict__ pl)
{
    __shared__ __align__(16) ushort_t P_lds[4][16][72];

    const int tid  = threadIdx.x;
    const int w    = tid >> 6;
    const int lane = tid & 63;
    const int l15  = lane & 15;
    const int lhi  = lane >> 4;
    const int h    = blockIdx.y;
    const int ks   = blockIdx.z;
    const int q0   = blockIdx.x * 64 + w * 16;
    const int kbase = ks * KCHUNK;

    const ushort_t* Kh = Kt + (size_t)h * NPTS * DHEAD;
    const ushort_t* Vh = Vt + (size_t)h * DHEAD * NPTS;

    bf16x8 qf0, qf1;
    {
        const ushort_t* qp = Qt + ((size_t)h * NPTS + q0 + l15) * DHEAD + lhi * 8;
        qf0 = *(const bf16x8*)qp;
        qf1 = *(const bf16x8*)(qp + 32);
    }

    f32x4 macc[4];
#pragma unroll
    for (int db = 0; db < 4; ++db) macc[db] = (f32x4){0.f, 0.f, 0.f, 0.f};
    float mrun[4], lrun[4];
#pragma unroll
    for (int r = 0; r < 4; ++r) { mrun[r] = -3.0e38f; lrun[r] = 0.0f; }

    for (int k0 = kbase; k0 < kbase + KCHUNK; k0 += 64) {
        // QK^T over 4 key-blocks of 16
        f32x4 sacc[4];
#pragma unroll
        for (int kb = 0; kb < 4; ++kb) {
            const ushort_t* kp = Kh + (size_t)(k0 + kb * 16 + l15) * DHEAD + lhi * 8;
            bf16x8 kf0 = *(const bf16x8*)kp;
            bf16x8 kf1 = *(const bf16x8*)(kp + 32);
            f32x4 z = (f32x4){0.f, 0.f, 0.f, 0.f};
            z = __builtin_amdgcn_mfma_f32_16x16x32_bf16(qf0, kf0, z, 0, 0, 0);
            z = __builtin_amdgcn_mfma_f32_16x16x32_bf16(qf1, kf1, z, 0, 0, 0);
            sacc[kb] = z;
        }

        // mask * scale, online softmax stats
        float p[4][4], tmax[4];
#pragma unroll
        for (int r = 0; r < 4; ++r) tmax[r] = -3.0e38f;
#pragma unroll
        for (int kb = 0; kb < 4; ++kb) {
#pragma unroll
            for (int r = 0; r < 4; ++r) {
                float mval = S[(size_t)(q0 + lhi * 4 + r) * NPTS + k0 + kb * 16 + l15];
                float sv = sacc[kb][r] * 0.125f * mval;
                p[kb][r] = sv;
                tmax[r] = fmaxf(tmax[r], sv);
            }
        }
#pragma unroll
        for (int r = 0; r < 4; ++r) {
            tmax[r] = fmaxf(tmax[r], __shfl_xor(tmax[r], 1));
            tmax[r] = fmaxf(tmax[r], __shfl_xor(tmax[r], 2));
            tmax[r] = fmaxf(tmax[r], __shfl_xor(tmax[r], 4));
            tmax[r] = fmaxf(tmax[r], __shfl_xor(tmax[r], 8));
        }
        float cf[4], tsum[4];
#pragma unroll
        for (int r = 0; r < 4; ++r) {
            float mn = fmaxf(mrun[r], tmax[r]);
            cf[r] = __expf(mrun[r] - mn);
            mrun[r] = mn;
            float s_ = 0.0f;
#pragma unroll
            for (int kb = 0; kb < 4; ++kb) {
                p[kb][r] = __expf(p[kb][r] - mn);
                s_ += p[kb][r];
            }
            tsum[r] = s_;
        }
#pragma unroll
        for (int r = 0; r < 4; ++r) {
            tsum[r] += __shfl_xor(tsum[r], 1);
            tsum[r] += __shfl_xor(tsum[r], 2);
            tsum[r] += __shfl_xor(tsum[r], 4);
            tsum[r] += __shfl_xor(tsum[r], 8);
            lrun[r] = lrun[r] * cf[r] + tsum[r];
        }
#pragma unroll
        for (int db = 0; db < 4; ++db)
#pragma unroll
            for (int r = 0; r < 4; ++r) macc[db][r] *= cf[r];

        // P (C-layout) -> bf16 -> per-warp LDS [q][k]
#pragma unroll
        for (int kb = 0; kb < 4; ++kb)
#pragma unroll
            for (int r = 0; r < 4; ++r)
                P_lds[w][lhi * 4 + r][kb * 16 + l15] = f2bf(p[kb][r]);

        // PV: 2 key-halves x 4 d-blocks
#pragma unroll
        for (int m = 0; m < 2; ++m) {
            bf16x8 pf = *(const bf16x8*)&P_lds[w][l15][m * 32 + lhi * 8];
#pragma unroll
            for (int db = 0; db < 4; ++db) {
                const ushort_t* vp = Vh + (size_t)(db * 16 + l15) * NPTS
                                   + k0 + m * 32 + lhi * 8;
                bf16x8 vf = *(const bf16x8*)vp;
                macc[db] = __builtin_amdgcn_mfma_f32_16x16x32_bf16(pf, vf, macc[db], 0, 0, 0);
            }
        }
    }

    // store unnormalized partials: pacc[(ks*4+h)*NPTS + q][d] bf16, pm/pl f32
    const size_t pb = ((size_t)ks * NHEAD + h) * NPTS;
#pragma unroll
    for (int db = 0; db < 4; ++db)
#pragma unroll
        for (int r = 0; r < 4; ++r)
            pacc[(pb + q0 + lhi * 4 + r) * DHEAD + db * 16 + l15] = f2bf(macc[db][r]);
    if (l15 == 0) {
#pragma unroll
        for (int r = 0; r < 4; ++r) {
            int q = q0 + lhi * 4 + r;
            pm[pb + q] = mrun[r];
            pl[pb + q] = lrun[r];
        }
    }
}

// ---------------------------------------------------------------------------
// Merge KSPLIT partials -> msgT [N][256] bf16 (channel-contiguous).
// Block = 256 thr = 64 q x 4 d-groups; grid (64, NHEAD).
// ---------------------------------------------------------------------------
__global__ __launch_bounds__(256) void attn_merge(
    const ushort_t* __restrict__ pacc, const float* __restrict__ pm,
    const float* __restrict__ pl, ushort_t* __restrict__ msgT)
{
    const int h = blockIdx.y;
    const int q = blockIdx.x * 64 + (threadIdx.x >> 2);
    const int d0 = (threadIdx.x & 3) * 16;

    float m[KSPLIT], l[KSPLIT];
#pragma unroll
    for (int ks = 0; ks < KSPLIT; ++ks) {
        size_t pb = ((size_t)ks * NHEAD + h) * NPTS + q;
        m[ks] = pm[pb];
        l[ks] = pl[pb];
    }
    float ms = fmaxf(fmaxf(m[0], m[1]), fmaxf(m[2], m[3]));
    float wgt[KSPLIT], ls = 0.0f;
#pragma unroll
    for (int ks = 0; ks < KSPLIT; ++ks) {
        wgt[ks] = __expf(m[ks] - ms);
        ls += wgt[ks] * l[ks];
    }
    float inv = 1.0f / ls;

    float out[16];
#pragma unroll
    for (int j = 0; j < 16; ++j) out[j] = 0.0f;
#pragma unroll
    for (int ks = 0; ks < KSPLIT; ++ks) {
        const ushort_t* ap = pacc + (((size_t)ks * NHEAD + h) * NPTS + q) * DHEAD + d0;
        bf16x8 v0 = *(const bf16x8*)ap;
        bf16x8 v1 = *(const bf16x8*)(ap + 8);
#pragma unroll
        for (int j = 0; j < 8; ++j) {
            out[j]     += wgt[ks] * bf2f((ushort_t)v0[j]);
            out[8 + j] += wgt[ks] * bf2f((ushort_t)v1[j]);
        }
    }
    bf16x8 o0, o1;
#pragma unroll
    for (int j = 0; j < 8; ++j) {
        o0[j] = (short)f2bf(out[j] * inv);
        o1[j] = (short)f2bf(out[8 + j] * inv);
    }
    ushort_t* op = msgT + (size_t)q * D_CH + h * DHEAD + d0;
    *(bf16x8*)op = o0;
    *(bf16x8*)(op + 8) = o1;
}

// ---------------------------------------------------------------------------
extern "C" void kernel_launch(void* const* d_in, const int* in_sizes, int n_in,
                              void* d_out, int out_size, void* d_ws, size_t ws_size,
                              hipStream_t stream) {
    const float* x  = (const float*)d_in[0];
    const float* S  = (const float*)d_in[1];
    const float* Wq = (const float*)d_in[2];
    const float* bq = (const float*)d_in[3];
    const float* Wk = (const float*)d_in[4];
    const float* bk = (const float*)d_in[5];
    const float* Wv = (const float*)d_in[6];
    const float* bv = (const float*)d_in[7];
    const float* W1 = (const float*)d_in[8];
    const float* b1 = (const float*)d_in[9];
    const float* g1 = (const float*)d_in[10];
    const float* be1= (const float*)d_in[11];
    const float* W2 = (const float*)d_in[12];
    const float* b2 = (const float*)d_in[13];
    const float* g2 = (const float*)d_in[14];
    const float* be2= (const float*)d_in[15];
    const float* W3 = (const float*)d_in[16];
    const float* b3 = (const float*)d_in[17];

    char* ws = (char*)d_ws;
    const size_t MB = 1024 * 1024;
    ushort_t* xT   = (ushort_t*)(ws);              // [4096][256] bf16, 2 MB
    ushort_t* Qt   = (ushort_t*)(ws + 2 * MB);     // [4][4096][64] bf16, 2 MB
    ushort_t* Kt   = (ushort_t*)(ws + 4 * MB);     // [4][4096][64] bf16, 2 MB
    ushort_t* Vt   = (ushort_t*)(ws + 6 * MB);     // [4][64][4096] bf16, 2 MB
    ushort_t* pacc = (ushort_t*)(ws + 8 * MB);     // [4][4][4096][64] bf16, 8 MB
    float*    pm   = (float*)   (ws + 16 * MB);            // 256 KB
    float*    pl   = (float*)   (ws + 16 * MB + 262144);   // 256 KB
    ushort_t* msgT = (ushort_t*)(ws + 16 * MB + 524288);   // [4096][256] bf16, 2 MB
    ushort_t* h1T  = (ushort_t*)(ws + 18 * MB + 524288);   // [4096][128] bf16, 1 MB
    ushort_t* h2T  = (ushort_t*)(ws + 19 * MB + 524288);   // [4096][128] bf16, 1 MB

    // prep: xT = cast(x^T)
    transpose_cast<<<dim3(64, 4), 256, 0, stream>>>(x, xT);

    // QKV projections (MFMA)
    gemm_mfma<<<dim3(64, 4), 256, 0, stream>>>(Wq, xT, Qt, 256, NPTS, 256, bq, nullptr, nullptr, 0, nullptr, 1);
    gemm_mfma<<<dim3(64, 4), 256, 0, stream>>>(Wk, xT, Kt, 256, NPTS, 256, bk, nullptr, nullptr, 0, nullptr, 1);
    gemm_mfma<<<dim3(64, 4), 256, 0, stream>>>(Wv, xT, Vt, 256, NPTS, 256, bv, nullptr, nullptr, 0, nullptr, 2);

    // key-split flash attention + merge
    attn_mfma<<<dim3(64, NHEAD, KSPLIT), 256, 0, stream>>>(Qt, Kt, Vt, S, pacc, pm, pl);
    attn_merge<<<dim3(64, NHEAD), 256, 0, stream>>>(pacc, pm, pl, msgT);

    // MLP (MFMA)
    gemm_mfma<<<dim3(64, 2), 256, 0, stream>>>(W1, msgT, h1T, 128, NPTS, 256, b1, g1, be1, 1, nullptr, 3);
    gemm_mfma<<<dim3(64, 2), 256, 0, stream>>>(W2, h1T, h2T, 128, NPTS, 128, b2, g2, be2, 1, nullptr, 3);
    gemm_mfma<<<dim3(64, 4), 256, 0, stream>>>(W3, h2T, d_out, 256, NPTS, 128, b3, nullptr, nullptr, 0, x, 0);
}